// Round 9
// baseline (1335.683 us; speedup 1.0000x reference)
//
#include <hip/hip_runtime.h>
#include <hip/hip_fp16.h>
#include <math.h>

#define HDIM 128
#define NSLOT 32     // stats copies to spread atomic contention
#define SEGSZ 12544  // histogram segment size (packed S|D counts, 50 KB LDS)
#define NSLICE 64    // edge slices for histogram

typedef _Float16 f16x8 __attribute__((ext_vector_type(8)));
typedef float f32x4 __attribute__((ext_vector_type(4)));
typedef int i32x4 __attribute__((ext_vector_type(4)));

// ev entry (4 B): low 16 bits = src node id (N<=65536), high 16 = fp16 weight.
__device__ __forceinline__ int ev_src(unsigned v) { return (int)(v & 0xffffu); }
__device__ __forceinline__ float ev_w(unsigned v) {
    return __half2float(__ushort_as_half((unsigned short)(v >> 16)));
}

// ------------- degree histograms, S|D packed in one LDS array ---------------
__global__ __launch_bounds__(256)
void hist_kernel(const int* __restrict__ src, const int* __restrict__ dst,
                 unsigned* __restrict__ partSD, int nseg, int N, int E) {
    __shared__ unsigned h[SEGSZ];
    int tid = threadIdx.x;
    int seg = blockIdx.x % nseg;
    int slice = blockIdx.x / nseg;
    int seg0 = seg * SEGSZ;
    for (int i = tid; i < SEGSZ; i += 256) h[i] = 0;
    __syncthreads();
    int chunk = (E + NSLICE - 1) / NSLICE;
    int e0 = slice * chunk;
    int e1 = min(E, e0 + chunk);
    for (int e = e0 + tid; e < e1; e += 256) {
        int s = src[e] - seg0;
        int d = dst[e] - seg0;
        if ((unsigned)s < SEGSZ) atomicAdd(&h[s], 1u);         // src count, low 16
        if ((unsigned)d < SEGSZ) atomicAdd(&h[d], 0x10000u);   // dst count, high 16
    }
    __syncthreads();
    for (int i = tid; i < SEGSZ; i += 256) {
        int node = seg0 + i;
        if (node < N) partSD[(size_t)slice * N + node] = h[i];
    }
}

// reduce packed partials -> dinv, degD, block sums (scanp1 fused), and pack
// the dim-3 input x into padded float4 xp for vectorized pull3 gathers.
__global__ __launch_bounds__(256)
void reduce_kernel(const unsigned* __restrict__ partSD,
                   const float* __restrict__ x, float4* __restrict__ xp,
                   float* __restrict__ dinv, int* __restrict__ degD,
                   int* __restrict__ bsum, int N) {
    __shared__ int sdata[256];
    int tid = threadIdx.x;
    int i = blockIdx.x * 256 + tid;
    int sD = 0;
    if (i < N) {
        int sS = 0;
#pragma unroll 8
        for (int k = 0; k < NSLICE; ++k) {
            unsigned v = partSD[(size_t)k * N + i];
            sS += (int)(v & 0xffffu);
            sD += (int)(v >> 16);
        }
        dinv[i] = sS > 0 ? rsqrtf((float)sS) : 0.f;
        degD[i] = sD;
        float4 xv;
        xv.x = x[3 * i + 0]; xv.y = x[3 * i + 1]; xv.z = x[3 * i + 2]; xv.w = 0.f;
        xp[i] = xv;
    }
    sdata[tid] = sD;
    __syncthreads();
    for (int off = 128; off > 0; off >>= 1) {
        if (tid < off) sdata[tid] += sdata[tid + off];
        __syncthreads();
    }
    if (tid == 0) bsum[blockIdx.x] = sdata[0];
}

__global__ __launch_bounds__(1024)
void scanp2_kernel(int* __restrict__ bsum, int nb) {
    __shared__ int part[1024];
    int tid = threadIdx.x;
    int v = tid < nb ? bsum[tid] : 0;
    part[tid] = v;
    __syncthreads();
    for (int off = 1; off < 1024; off <<= 1) {
        int t = tid >= off ? part[tid - off] : 0;
        __syncthreads();
        part[tid] += t;
        __syncthreads();
    }
    if (tid < nb) bsum[tid] = part[tid] - v;   // exclusive
}

// rp + cursor both get the exclusive prefix (cursor doubles as scatter's
// absolute write pointer -> no rp load, no cursor memset).
__global__ void scanp3_kernel(const int* __restrict__ deg, const int* __restrict__ bsum,
                              int* __restrict__ rp, int* __restrict__ cursor, int N, int E) {
    __shared__ int part[256];
    int tid = threadIdx.x;
    int i = blockIdx.x * 256 + tid;
    int v = i < N ? deg[i] : 0;
    part[tid] = v;
    __syncthreads();
    for (int off = 1; off < 256; off <<= 1) {
        int t = tid >= off ? part[tid - off] : 0;
        __syncthreads();
        part[tid] += t;
        __syncthreads();
    }
    if (i < N) {
        int r = bsum[blockIdx.x] + part[tid] - v;
        rp[i] = r;
        cursor[i] = r;
    }
    if (i == 0) rp[N] = E;
}

__global__ void scatter_kernel(const int* __restrict__ src, const int* __restrict__ dst,
                               const float* __restrict__ dinv,
                               int* __restrict__ cursor, unsigned* __restrict__ ev, int E) {
    int e = blockIdx.x * blockDim.x + threadIdx.x;
    if (e >= E) return;
    int s = src[e], d = dst[e];
    float w = -dinv[s] * dinv[d];
    int pos = atomicAdd(&cursor[d], 1);    // absolute position (cursor init = rp)
    unsigned val = ((unsigned)__half_as_ushort(__float2half(w)) << 16) | (unsigned)s;
    ev[pos] = val;
}

// ------- bucketize: stable-partition each node's bucket by src tile ---------
// 1 node/wave. ev -> ev2; bnd[node] = start offsets of tiles 0..3 (tile 0
// start == rp[node]; tile t ends at next start; tile 3 ends at rp[node+1]).
__global__ __launch_bounds__(256)
void bucketize_kernel(const unsigned* __restrict__ ev, const int* __restrict__ rp,
                      unsigned* __restrict__ ev2, int4* __restrict__ bnd,
                      int TQ, int N) {
    int node = blockIdx.x * 4 + (threadIdx.x >> 6);
    if (node >= N) return;
    int lane = threadIdx.x & 63;
    int b = rp[node], e = rp[node + 1];
    int cnt[4] = {0, 0, 0, 0};
    for (int j = b; j < e; j += 64) {
        int idx = j + lane;
        int tile = -1;
        if (idx < e) tile = ev_src(ev[idx]) / TQ;
#pragma unroll
        for (int t = 0; t < 4; ++t)
            cnt[t] += __popcll(__ballot(tile == t));
    }
    int st0 = b;
    int st1 = st0 + cnt[0];
    int st2 = st1 + cnt[1];
    int st3 = st2 + cnt[2];
    if (lane == 0) bnd[node] = make_int4(st0, st1, st2, st3);
    int run[4] = {st0, st1, st2, st3};
    for (int j = b; j < e; j += 64) {
        int idx = j + lane;
        unsigned v = 0u;
        int tile = -1;
        if (idx < e) { v = ev[idx]; tile = ev_src(v) / TQ; }
        int pos = -1;
#pragma unroll
        for (int t = 0; t < 4; ++t) {
            unsigned long long m = __ballot(tile == t);
            if (tile == t)
                pos = run[t] + __popcll(m & ((1ull << lane) - 1ull));
            run[t] += __popcll(m);
        }
        if (idx < e) ev2[pos] = v;
    }
}

// ---------------- tile-phased pull: out = L * g(t) --------------------------
// 64 nodes/block, LDS fp32 accumulators, all blocks co-resident (33 KB LDS ->
// 4 blocks/CU). Phase p processes only edges whose src lies in tile p
// (3.2 MB, fits per-XCD L2); __syncthreads per phase keeps the block aligned
// so the whole chip gathers from one tile at a time.
template <int GBN>
__global__ __launch_bounds__(256)
void pullT(const __half* __restrict__ t, const int* __restrict__ rp,
           const int4* __restrict__ bnd, const unsigned* __restrict__ ev,
           const float* __restrict__ bnp, __half* __restrict__ outp, int N) {
    __shared__ float acc[64][132];
    int tid = threadIdx.x;
    int wave = tid >> 6, lane = tid & 63;
    int node0 = blockIdx.x * 64;
    int c8 = (lane & 15) * 8;
    int slot = lane >> 4;
    const _Float16* tp = (const _Float16*)t;

    float scv[8], shv[8];
    if (GBN) {
#pragma unroll
        for (int i = 0; i < 8; ++i) { scv[i] = bnp[c8 + i]; shv[i] = bnp[128 + c8 + i]; }
    }
    for (int i = tid; i < 64 * 132; i += 256) ((float*)acc)[i] = 0.f;
    __syncthreads();

#pragma unroll
    for (int p = 0; p < 4; ++p) {
        for (int n = 0; n < 16; ++n) {
            int nl = wave * 16 + n;
            int node = node0 + nl;
            if (node >= N) break;
            int4 bv = bnd[node];
            int s  = p == 0 ? bv.x : p == 1 ? bv.y : p == 2 ? bv.z : bv.w;
            int e2 = p == 0 ? bv.y : p == 1 ? bv.z : p == 2 ? bv.w : rp[node + 1];
            float a[8] = {};
            int j = s;
            for (; j + 8 <= e2; j += 8) {
                unsigned v0 = ev[j + slot];
                unsigned v1 = ev[j + 4 + slot];
                f16x8 r0 = *(const f16x8*)(tp + (size_t)ev_src(v0) * HDIM + c8);
                f16x8 r1 = *(const f16x8*)(tp + (size_t)ev_src(v1) * HDIM + c8);
                float w0 = ev_w(v0), w1 = ev_w(v1);
#pragma unroll
                for (int i = 0; i < 8; ++i) {
                    float x0 = (float)r0[i], x1 = (float)r1[i];
                    if (GBN) { x0 = x0 * scv[i] + shv[i]; x1 = x1 * scv[i] + shv[i]; }
                    a[i] += w0 * x0 + w1 * x1;
                }
            }
            for (; j < e2; j += 4) {
                int idx = j + slot;
                if (idx < e2) {
                    unsigned v0 = ev[idx];
                    f16x8 r0 = *(const f16x8*)(tp + (size_t)ev_src(v0) * HDIM + c8);
                    float w0 = ev_w(v0);
#pragma unroll
                    for (int i = 0; i < 8; ++i) {
                        float x0 = (float)r0[i];
                        if (GBN) x0 = x0 * scv[i] + shv[i];
                        a[i] += w0 * x0;
                    }
                }
            }
#pragma unroll
            for (int i = 0; i < 8; ++i) {
                a[i] += __shfl_xor(a[i], 16);
                a[i] += __shfl_xor(a[i], 32);
            }
            if (lane < 16) {
#pragma unroll
                for (int i = 0; i < 8; ++i) acc[nl][c8 + i] += a[i];
            }
        }
        __syncthreads();
    }

    // write out: 64 nodes x 16 chunks of 8 fp16
    for (int i = tid; i < 64 * 16; i += 256) {
        int nl = i >> 4, co = (i & 15) * 8;
        int node = node0 + nl;
        if (node < N) {
            f16x8 h;
#pragma unroll
            for (int k = 0; k < 8; ++k) h[k] = (_Float16)acc[nl][co + k];
            *(f16x8*)((_Float16*)outp + (size_t)node * HDIM + co) = h;
        }
    }
}

// dim-3 pull on float4-padded tables: ONE 16 B gather per edge.
__global__ void pull3(const float4* __restrict__ t, const float4* __restrict__ prev,
                      const int* __restrict__ rp, const unsigned* __restrict__ ev,
                      float4* __restrict__ outp, float alpha, int N) {
    int node = blockIdx.x * blockDim.x + threadIdx.x;
    if (node >= N) return;
    int b = rp[node], e = rp[node + 1];
    float a0 = 0.f, a1 = 0.f, a2 = 0.f;
    for (int j = b; j < e; ++j) {
        unsigned v = ev[j];
        float w = ev_w(v);
        float4 r = t[ev_src(v)];
        a0 += w * r.x; a1 += w * r.y; a2 += w * r.z;
    }
    float4 o;
    o.x = alpha * a0; o.y = alpha * a1; o.z = alpha * a2; o.w = 0.f;
    if (prev) {
        float4 p = prev[node];
        o.x -= p.x; o.y -= p.y; o.z -= p.z;
    }
    outp[node] = o;
}

// ---------------- fused BN-finalize + weight prep + bias --------------------
__global__ __launch_bounds__(256)
void wfuse_kernel(const float* __restrict__ stats, const float* __restrict__ g,
                  const float* __restrict__ be, const float* __restrict__ W,
                  const float* __restrict__ b, _Float16* __restrict__ Wt,
                  float* __restrict__ bias2, float* __restrict__ bnp, float invN) {
    int tid = threadIdx.x;
    if (blockIdx.x < 256) {
        int idx = blockIdx.x * 256 + tid;   // 65536 = n(128) x k(512)
        int n = idx >> 9, k = idx & 511;
        int sel = k >> 7, kk = k & 127;
        int o = kk * 128 + n;
        float v;
        if (sel == 0) {
            float s0 = 0.f, s1 = 0.f;
#pragma unroll 4
            for (int t = 0; t < NSLOT; ++t) {
                s0 += stats[t * 256 + kk];
                s1 += stats[t * 256 + 128 + kk];
            }
            float m = s0 * invN;
            float var = s1 * invN - m * m;
            float sc = g[kk] * rsqrtf(var + 1e-5f);
            v = (W[o] - W[2 * 16384 + o]) * sc;
        } else if (sel == 1) v = W[16384 + o] - 3.f * W[3 * 16384 + o];
        else if (sel == 2)   v = 2.f * W[2 * 16384 + o];
        else                 v = 4.f * W[3 * 16384 + o];
        Wt[(size_t)((k >> 3) * 128 + n) * 8 + (k & 7)] = (_Float16)v;
    } else {
        __shared__ float sh[128];
        if (tid < 128) {
            float s0 = 0.f, s1 = 0.f;
#pragma unroll 4
            for (int t = 0; t < NSLOT; ++t) {
                s0 += stats[t * 256 + tid];
                s1 += stats[t * 256 + 128 + tid];
            }
            float m = s0 * invN;
            float var = s1 * invN - m * m;
            float sc = g[tid] * rsqrtf(var + 1e-5f);
            float shf = be[tid] - m * sc;
            bnp[tid] = sc;
            bnp[128 + tid] = shf;
            sh[tid] = shf;
        }
        __syncthreads();
        if (tid < 128) {
            float s = b[tid];
            for (int k = 0; k < 128; ++k)
                s += sh[k] * (W[k * 128 + tid] - W[2 * 16384 + k * 128 + tid]);
            bias2[tid] = s;
        }
    }
}

// ---------------- MFMA Cheb GEMM, LDS-staged A, fused BN-stats epilogue -----
template <int ACT, int OUTH, int STATS>
__global__ __launch_bounds__(256)
void gemm_mfma(const __half* __restrict__ T0, const __half* __restrict__ T1,
               const __half* __restrict__ T2, const __half* __restrict__ T3,
               const _Float16* __restrict__ Wt, const float* __restrict__ bias2,
               __half* __restrict__ outh, float* __restrict__ outf,
               float* __restrict__ stats, int N) {
    __shared__ __align__(16) _Float16 As[4][32][136];
    __shared__ float s_sum[128];
    __shared__ float s_sq[128];
    int tid = threadIdx.x;
    int wave = tid >> 6, lane = tid & 63;
    int row0 = blockIdx.x * 32;

    if (STATS && tid < 128) { s_sum[tid] = 0.f; s_sq[tid] = 0.f; }

    // ---- stage A: wave w loads table w (32 rows x 128 ch fp16 = 8 KB) ----
    {
        const __half* Ts[4] = {T0, T1, T2, T3};
        const _Float16* Tp = (const _Float16*)Ts[wave];
        int lr = lane >> 4;           // row-sub 0..3
        int ko = (lane & 15) * 8;     // k offset (halves)
        f16x8 v[8];
#pragma unroll
        for (int t = 0; t < 8; ++t) {
            int gr = min(row0 + t * 4 + lr, N - 1);
            v[t] = *(const f16x8*)(Tp + (size_t)gr * HDIM + ko);
        }
#pragma unroll
        for (int t = 0; t < 8; ++t)
            *(f16x8*)&As[wave][t * 4 + lr][ko] = v[t];
    }
    __syncthreads();

    int wr = wave >> 1, wc = wave & 1;
    int m = lane & 15, quad = lane >> 4;
    int nbase = wc * 64 + m;

    f32x4 acc[4];
#pragma unroll
    for (int ct = 0; ct < 4; ++ct) acc[ct] = (f32x4){0.f, 0.f, 0.f, 0.f};

#pragma unroll
    for (int kt = 0; kt < 4; ++kt) {
#pragma unroll
        for (int sel = 0; sel < 4; ++sel) {
            f16x8 a = *(const f16x8*)&As[sel][wr * 16 + m][kt * 32 + quad * 8];
            int c0 = sel * 16 + kt * 4 + quad;        // k-chunk index
#pragma unroll
            for (int ct = 0; ct < 4; ++ct) {
                f16x8 b0 = *(const f16x8*)(Wt + ((size_t)c0 * 128 + nbase + ct * 16) * 8);
                acc[ct] = __builtin_amdgcn_mfma_f32_16x16x32_f16(a, b0, acc[ct], 0, 0, 0);
            }
        }
    }

    // epilogue (+ optional per-column stats accumulation)
#pragma unroll
    for (int ct = 0; ct < 4; ++ct) {
        int col = wc * 64 + ct * 16 + m;
        float bv = bias2[col];
        float lsum = 0.f, lsq = 0.f;
#pragma unroll
        for (int r = 0; r < 4; ++r) {
            int drow = row0 + wr * 16 + quad * 4 + r;
            if (drow < N) {
                float v = acc[ct][r] + bv;
                if (ACT == 1) v = v >= 0.f ? v : 0.01f * v;
                else if (ACT == 2) v = fmaxf(v, 0.f);
                if (OUTH) outh[(size_t)drow * HDIM + col] = __float2half(v);
                else      outf[(size_t)drow * HDIM + col] = v;
                if (STATS) {
                    float vh = OUTH ? __half2float(__float2half(v)) : v;
                    lsum += vh; lsq += vh * vh;
                }
            }
        }
        if (STATS) {
            atomicAdd(&s_sum[col], lsum);
            atomicAdd(&s_sq[col], lsq);
        }
    }
    if (STATS) {
        __syncthreads();
        if (tid < 128) {
            float* sp = stats + (size_t)(blockIdx.x & (NSLOT - 1)) * 256;
            atomicAdd(&sp[tid], s_sum[tid]);
            atomicAdd(&sp[128 + tid], s_sq[tid]);
        }
    }
}

// ---------------- layer-1 (input dim 3, padded tables) ----------------------
__global__ __launch_bounds__(256)
void gemm1_kernel(const float4* __restrict__ x, const float4* __restrict__ t1,
                  const float4* __restrict__ t2, const float4* __restrict__ t3,
                  const float* __restrict__ W1, const float* __restrict__ b1,
                  __half* __restrict__ out, float* __restrict__ stats, int N) {
    __shared__ float s_sum[128];
    __shared__ float s_sq[128];
    int tid = threadIdx.x;
    int c = tid & 127;
    if (tid < 128) { s_sum[tid] = 0.f; s_sq[tid] = 0.f; }
    __syncthreads();
    float wreg[12];
#pragma unroll
    for (int i = 0; i < 12; ++i) wreg[i] = W1[i * 128 + c];
    float bias = b1[c];
    const float4* Ts[4] = {x, t1, t2, t3};
    float lsum = 0.f, lsq = 0.f;
    for (int row = blockIdx.x * 2 + (tid >> 7); row < N; row += gridDim.x * 2) {
        float v = bias;
#pragma unroll
        for (int k = 0; k < 4; ++k) {
            float4 r = Ts[k][row];
            v += r.x * wreg[k * 3 + 0] + r.y * wreg[k * 3 + 1] + r.z * wreg[k * 3 + 2];
        }
        v = v >= 0.f ? v : 0.01f * v;   // leaky_relu
        out[(size_t)row * HDIM + c] = __float2half(v);
        lsum += v; lsq += v * v;
    }
    atomicAdd(&s_sum[c], lsum);
    atomicAdd(&s_sq[c], lsq);
    __syncthreads();
    if (tid < 128) {
        float* sp = stats + (size_t)(blockIdx.x & (NSLOT - 1)) * 256;
        atomicAdd(&sp[tid], s_sum[tid]);
        atomicAdd(&sp[128 + tid], s_sq[tid]);
    }
}

// ---------------- final: L2-normalize row + project to 3 ----------------
__global__ void final_kernel(const float* __restrict__ Z, const float* __restrict__ Wm,
                             const float* __restrict__ bm, float* __restrict__ out, int N) {
    int gid = blockIdx.x * blockDim.x + threadIdx.x;
    int node = gid >> 6;
    int lane = threadIdx.x & 63;
    if (node >= N) return;
    const float* z = Z + (size_t)node * HDIM;
    float z0 = z[lane], z1 = z[lane + 64];
    float sq = z0 * z0 + z1 * z1;
    float d0 = z0 * Wm[lane * 3 + 0] + z1 * Wm[(lane + 64) * 3 + 0];
    float d1 = z0 * Wm[lane * 3 + 1] + z1 * Wm[(lane + 64) * 3 + 1];
    float d2 = z0 * Wm[lane * 3 + 2] + z1 * Wm[(lane + 64) * 3 + 2];
#pragma unroll
    for (int off = 32; off > 0; off >>= 1) {
        sq += __shfl_down(sq, off);
        d0 += __shfl_down(d0, off);
        d1 += __shfl_down(d1, off);
        d2 += __shfl_down(d2, off);
    }
    if (lane == 0) {
        float inv = 1.f / fmaxf(sqrtf(sq), 1e-12f);
        out[node * 3 + 0] = d0 * inv + bm[0];
        out[node * 3 + 1] = d1 * inv + bm[1];
        out[node * 3 + 2] = d2 * inv + bm[2];
    }
}

// ---------------- host ----------------

extern "C" void kernel_launch(void* const* d_in, const int* in_sizes, int n_in,
                              void* d_out, int out_size, void* d_ws, size_t ws_size,
                              hipStream_t stream) {
    const float* x  = (const float*)d_in[0];
    const int*   ei = (const int*)d_in[1];
    const float* W1 = (const float*)d_in[2];
    const float* b1 = (const float*)d_in[3];
    const float* W2 = (const float*)d_in[4];
    const float* b2 = (const float*)d_in[5];
    const float* W3 = (const float*)d_in[6];
    const float* b3 = (const float*)d_in[7];
    const float* W4 = (const float*)d_in[8];
    const float* b4 = (const float*)d_in[9];
    const float* g1 = (const float*)d_in[10];
    const float* be1 = (const float*)d_in[11];
    const float* g2 = (const float*)d_in[12];
    const float* be2 = (const float*)d_in[13];
    const float* g3 = (const float*)d_in[14];
    const float* be3 = (const float*)d_in[15];
    const float* Wm = (const float*)d_in[16];
    const float* bm = (const float*)d_in[17];
    float* out = (float*)d_out;

    const int N = in_sizes[0] / 3;
    const int E = in_sizes[1] / 2;
    const size_t NH = (size_t)N * HDIM;
    const int* src = ei;
    const int* dst = ei + E;

    const size_t STB = (size_t)NSLOT * 256 * 4;

    // ---- workspace layout (3 stats buffers first: one upfront memset) ----
    char* base = (char*)d_ws;
    float* statsA = (float*)base;        base += STB;
    float* statsB = (float*)base;        base += STB;
    float* statsC = (float*)base;        base += STB;
    const size_t ZB = 3 * STB;

    unsigned* partSD = (unsigned*)base;  base += (size_t)NSLICE * N * 4;
    int* degD   = (int*)base;            base += (size_t)N * 4;
    int* cursor = (int*)base;            base += (size_t)N * 4;
    int* rp     = (int*)base;            base += (size_t)(N + 2) * 4;
    int* bsum   = (int*)base;            base += (size_t)1024 * 4;
    unsigned* ev = (unsigned*)base;      base += (size_t)E * 4;
    unsigned* ev2 = (unsigned*)base;     base += (size_t)E * 4;
    int4* bnd   = (int4*)base;           base += (size_t)N * 16;
    float* dinv = (float*)base;          base += (size_t)N * 4;
    __half* Za  = (__half*)base;         base += NH * 2;
    __half* Zb  = (__half*)base;         base += NH * 2;
    __half* T1  = (__half*)base;         base += NH * 2;
    __half* T2  = (__half*)base;         base += NH * 2;
    __half* T3  = (__half*)base;         base += NH * 2;
    float* Zf   = (float*)base;          base += NH * 4;   // layer-4 out, fp32
    float4* xp  = (float4*)base;         base += (size_t)N * 16;
    float4* x1  = (float4*)base;         base += (size_t)N * 16;
    float4* x2  = (float4*)base;         base += (size_t)N * 16;
    float4* x3  = (float4*)base;         base += (size_t)N * 16;
    float* bnp1  = (float*)base;         base += 256 * 4;
    float* bnp2  = (float*)base;         base += 256 * 4;
    float* bnp3  = (float*)base;         base += 256 * 4;
    _Float16* Wt = (_Float16*)base;      base += (size_t)65536 * 2;
    float* bias2 = (float*)base;         base += 128 * 4;

    const int EB = (E + 255) / 256;
    const int NB = (N + 255) / 256;
    const int GB = (N + 31) / 32;         // mfma gemm row tiles (32 rows)
    const int PB = (N + 3) / 4;           // bucketize blocks (4 nodes/block)
    const int TB = (N + 63) / 64;         // pullT blocks (64 nodes/block)
    const int TQ = (N + 3) / 4;           // src tile width (rows)
    const int NSEG = (N + SEGSZ - 1) / SEGSZ;
    const float invN = 1.f / (float)N;

    // --- single upfront zero of the stats buffers ---
    hipMemsetAsync(statsA, 0, ZB, stream);

    // --- CSR build + edge weights + tile bucketize ---
    hist_kernel<<<NSEG * NSLICE, 256, 0, stream>>>(src, dst, partSD, NSEG, N, E);
    reduce_kernel<<<NB, 256, 0, stream>>>(partSD, x, xp, dinv, degD, bsum, N);
    scanp2_kernel<<<1, 1024, 0, stream>>>(bsum, NB);
    scanp3_kernel<<<NB, 256, 0, stream>>>(degD, bsum, rp, cursor, N, E);
    scatter_kernel<<<EB, 256, 0, stream>>>(src, dst, dinv, cursor, ev, E);
    bucketize_kernel<<<PB, 256, 0, stream>>>(ev, rp, ev2, bnd, TQ, N);

    // --- layer 1 (dim 3, padded) -> Za (fp16) + statsA ---
    pull3<<<NB, 256, 0, stream>>>(xp, nullptr, rp, ev2, x1, 1.f, N);
    pull3<<<NB, 256, 0, stream>>>(x1, xp,      rp, ev2, x2, 2.f, N);
    pull3<<<NB, 256, 0, stream>>>(x2, x1,      rp, ev2, x3, 2.f, N);
    gemm1_kernel<<<512, 256, 0, stream>>>(xp, x1, x2, x3, W1, b1, Za, statsA, N);

    // --- layer 2 (leaky + BN): U-chain from BN(Za,bnp1) -> Zb (stats -> B) ---
    wfuse_kernel<<<257, 256, 0, stream>>>(statsA, g1, be1, W2, b2, Wt, bias2, bnp1, invN);
    pullT<1><<<TB, 256, 0, stream>>>(Za, rp, bnd, ev2, bnp1, T1, N);
    pullT<0><<<TB, 256, 0, stream>>>(T1, rp, bnd, ev2, nullptr, T2, N);
    pullT<0><<<TB, 256, 0, stream>>>(T2, rp, bnd, ev2, nullptr, T3, N);
    gemm_mfma<1, 1, 1><<<GB, 256, 0, stream>>>(Za, T1, T2, T3, Wt, bias2, Zb, nullptr, statsB, N);

    // --- layer 3 (relu + BN): U-chain from BN(Zb,bnp2) -> Za (stats -> C) ---
    wfuse_kernel<<<257, 256, 0, stream>>>(statsB, g2, be2, W3, b3, Wt, bias2, bnp2, invN);
    pullT<1><<<TB, 256, 0, stream>>>(Zb, rp, bnd, ev2, bnp2, T1, N);
    pullT<0><<<TB, 256, 0, stream>>>(T1, rp, bnd, ev2, nullptr, T2, N);
    pullT<0><<<TB, 256, 0, stream>>>(T2, rp, bnd, ev2, nullptr, T3, N);
    gemm_mfma<2, 1, 1><<<GB, 256, 0, stream>>>(Zb, T1, T2, T3, Wt, bias2, Za, nullptr, statsC, N);

    // --- layer 4 (no act/BN): U-chain from BN(Za,bnp3) -> Zf (fp32) ---
    wfuse_kernel<<<257, 256, 0, stream>>>(statsC, g3, be3, W4, b4, Wt, bias2, bnp3, invN);
    pullT<1><<<TB, 256, 0, stream>>>(Za, rp, bnd, ev2, bnp3, T1, N);
    pullT<0><<<TB, 256, 0, stream>>>(T1, rp, bnd, ev2, nullptr, T2, N);
    pullT<0><<<TB, 256, 0, stream>>>(T2, rp, bnd, ev2, nullptr, T3, N);
    gemm_mfma<0, 0, 0><<<GB, 256, 0, stream>>>(Za, T1, T2, T3, Wt, bias2, nullptr, Zf, nullptr, N);

    // --- normalize + project ---
    final_kernel<<<(N * 64 + 255) / 256, 256, 0, stream>>>(Zf, Wm, bm, out, N);
}

// Round 10
// 680.572 us; speedup vs baseline: 1.9626x; 1.9626x over previous
//
#include <hip/hip_runtime.h>
#include <hip/hip_fp16.h>
#include <math.h>

#define HDIM 128
#define NSLOT 32    // stats copies to spread atomic contention
#define SEGSZ 6272  // histogram segment size (LDS ints)
#define NSLICE 64   // edge slices for histogram

typedef _Float16 f16x8 __attribute__((ext_vector_type(8)));
typedef float f32x4 __attribute__((ext_vector_type(4)));
typedef int i32x4 __attribute__((ext_vector_type(4)));

// ev entry (4 B): low 16 bits = src node id (N<=65536), high 16 = fp16 weight.
__device__ __forceinline__ int ev_src(unsigned v) { return (int)(v & 0xffffu); }
__device__ __forceinline__ float ev_w(unsigned v) {
    return __half2float(__ushort_as_half((unsigned short)(v >> 16)));
}

// ---------------- degree histograms via LDS segments (no global atomics) ----
__global__ __launch_bounds__(256)
void hist_kernel(const int* __restrict__ src, const int* __restrict__ dst,
                 int* __restrict__ partS, int* __restrict__ partD,
                 int nseg, int N, int E) {
    __shared__ int hS[SEGSZ];
    __shared__ int hD[SEGSZ];
    int tid = threadIdx.x;
    int seg = blockIdx.x % nseg;
    int slice = blockIdx.x / nseg;
    int seg0 = seg * SEGSZ;
    for (int i = tid; i < SEGSZ; i += 256) { hS[i] = 0; hD[i] = 0; }
    __syncthreads();
    int chunk = (E + NSLICE - 1) / NSLICE;
    int e0 = slice * chunk;
    int e1 = min(E, e0 + chunk);
    for (int e = e0 + tid; e < e1; e += 256) {
        int s = src[e] - seg0;
        int d = dst[e] - seg0;
        if ((unsigned)s < SEGSZ) atomicAdd(&hS[s], 1);
        if ((unsigned)d < SEGSZ) atomicAdd(&hD[d], 1);
    }
    __syncthreads();
    for (int i = tid; i < SEGSZ; i += 256) {
        int node = seg0 + i;
        if (node < N) {
            partS[(size_t)slice * N + node] = hS[i];
            partD[(size_t)slice * N + node] = hD[i];
        }
    }
}

// reduce partials -> dinv (fused rsqrt), degD, and per-block sums (scanp1 fused)
__global__ __launch_bounds__(256)
void reduce_kernel(const int* __restrict__ partS, const int* __restrict__ partD,
                   float* __restrict__ dinv, int* __restrict__ degD,
                   int* __restrict__ bsum, int N) {
    __shared__ int sdata[256];
    int tid = threadIdx.x;
    int i = blockIdx.x * 256 + tid;
    int sD = 0;
    if (i < N) {
        int sS = 0;
#pragma unroll 8
        for (int k = 0; k < NSLICE; ++k) {
            sS += partS[(size_t)k * N + i];
            sD += partD[(size_t)k * N + i];
        }
        dinv[i] = sS > 0 ? rsqrtf((float)sS) : 0.f;
        degD[i] = sD;
    }
    sdata[tid] = sD;
    __syncthreads();
    for (int off = 128; off > 0; off >>= 1) {
        if (tid < off) sdata[tid] += sdata[tid + off];
        __syncthreads();
    }
    if (tid == 0) bsum[blockIdx.x] = sdata[0];
}

__global__ __launch_bounds__(1024)
void scanp2_kernel(int* __restrict__ bsum, int nb) {
    __shared__ int part[1024];
    int tid = threadIdx.x;
    int v = tid < nb ? bsum[tid] : 0;
    part[tid] = v;
    __syncthreads();
    for (int off = 1; off < 1024; off <<= 1) {
        int t = tid >= off ? part[tid - off] : 0;
        __syncthreads();
        part[tid] += t;
        __syncthreads();
    }
    if (tid < nb) bsum[tid] = part[tid] - v;   // exclusive
}

__global__ void scanp3_kernel(const int* __restrict__ deg, const int* __restrict__ bsum,
                              int* __restrict__ rp, int N, int E) {
    __shared__ int part[256];
    int tid = threadIdx.x;
    int i = blockIdx.x * 256 + tid;
    int v = i < N ? deg[i] : 0;
    part[tid] = v;
    __syncthreads();
    for (int off = 1; off < 256; off <<= 1) {
        int t = tid >= off ? part[tid - off] : 0;
        __syncthreads();
        part[tid] += t;
        __syncthreads();
    }
    if (i < N) rp[i] = bsum[blockIdx.x] + part[tid] - v;
    if (i == 0) rp[N] = E;
}

__global__ void scatter_kernel(const int* __restrict__ src, const int* __restrict__ dst,
                               const float* __restrict__ dinv, const int* __restrict__ rp,
                               int* __restrict__ cursor, unsigned* __restrict__ ev, int E) {
    int e = blockIdx.x * blockDim.x + threadIdx.x;
    if (e >= E) return;
    int s = src[e], d = dst[e];
    float w = -dinv[s] * dinv[d];
    int pos = atomicAdd(&cursor[d], 1);
    unsigned val = ((unsigned)__half_as_ushort(__float2half(w)) << 16) | (unsigned)s;
    ev[rp[d] + pos] = val;
}

// ---------------- pure pull: out = L * g(t), row-major 256B rows ------------
// 1 node/wave, 4 nodes/block. 16 ch-groups x 4 edge slots; 4 gathers in
// flight. All loads cached (ev is re-read by later pulls; tables are the
// next pull's gather source).
template <int GBN>
__global__ __launch_bounds__(256)
void pull128(const __half* __restrict__ t, const int* __restrict__ rp,
             const unsigned* __restrict__ ev, const float* __restrict__ bnp,
             __half* __restrict__ outp, int N) {
    int node = blockIdx.x * 4 + (threadIdx.x >> 6);
    if (node >= N) return;
    int lane = threadIdx.x & 63;
    int c8 = (lane & 15) * 8;     // 8-channel group
    int slot = lane >> 4;         // edge slot 0..3
    const _Float16* tp = (const _Float16*)t;

    float scv[8], shv[8];
    if (GBN) {
#pragma unroll
        for (int i = 0; i < 8; ++i) { scv[i] = bnp[c8 + i]; shv[i] = bnp[128 + c8 + i]; }
    }

    int b = rp[node], e = rp[node + 1];
    float acc0[8] = {}, acc1[8] = {};
    int j = b;
    // 16 edges/iter: 4 independent gathers in flight
    for (; j + 16 <= e; j += 16) {
        unsigned v0 = ev[j + slot];
        unsigned v1 = ev[j + 4 + slot];
        unsigned v2 = ev[j + 8 + slot];
        unsigned v3 = ev[j + 12 + slot];
        f16x8 r0 = *(const f16x8*)(tp + (size_t)ev_src(v0) * HDIM + c8);
        f16x8 r1 = *(const f16x8*)(tp + (size_t)ev_src(v1) * HDIM + c8);
        f16x8 r2 = *(const f16x8*)(tp + (size_t)ev_src(v2) * HDIM + c8);
        f16x8 r3 = *(const f16x8*)(tp + (size_t)ev_src(v3) * HDIM + c8);
        float w0 = ev_w(v0), w1 = ev_w(v1), w2 = ev_w(v2), w3 = ev_w(v3);
#pragma unroll
        for (int i = 0; i < 8; ++i) {
            float a0 = (float)r0[i], a1 = (float)r1[i];
            float a2 = (float)r2[i], a3 = (float)r3[i];
            if (GBN) {
                a0 = a0 * scv[i] + shv[i]; a1 = a1 * scv[i] + shv[i];
                a2 = a2 * scv[i] + shv[i]; a3 = a3 * scv[i] + shv[i];
            }
            acc0[i] += w0 * a0; acc1[i] += w1 * a1;
            acc0[i] += w2 * a2; acc1[i] += w3 * a3;
        }
    }
    if (j + 8 <= e) {
        unsigned v0 = ev[j + slot];
        unsigned v1 = ev[j + 4 + slot];
        f16x8 r0 = *(const f16x8*)(tp + (size_t)ev_src(v0) * HDIM + c8);
        f16x8 r1 = *(const f16x8*)(tp + (size_t)ev_src(v1) * HDIM + c8);
        float w0 = ev_w(v0), w1 = ev_w(v1);
#pragma unroll
        for (int i = 0; i < 8; ++i) {
            float a0 = (float)r0[i], a1 = (float)r1[i];
            if (GBN) { a0 = a0 * scv[i] + shv[i]; a1 = a1 * scv[i] + shv[i]; }
            acc0[i] += w0 * a0; acc1[i] += w1 * a1;
        }
        j += 8;
    }
    for (; j < e; j += 4) {
        int idx = j + slot;
        if (idx < e) {
            unsigned v0 = ev[idx];
            f16x8 r0 = *(const f16x8*)(tp + (size_t)ev_src(v0) * HDIM + c8);
            float w0 = ev_w(v0);
#pragma unroll
            for (int i = 0; i < 8; ++i) {
                float a0 = (float)r0[i];
                if (GBN) a0 = a0 * scv[i] + shv[i];
                acc0[i] += w0 * a0;
            }
        }
    }
    float s[8];
#pragma unroll
    for (int i = 0; i < 8; ++i) {
        s[i] = acc0[i] + acc1[i];
        s[i] += __shfl_xor(s[i], 16);
        s[i] += __shfl_xor(s[i], 32);
    }
    if (lane < 16) {
        size_t o = (size_t)node * HDIM + c8;
        f16x8 h;
#pragma unroll
        for (int i = 0; i < 8; ++i) h[i] = (_Float16)s[i];
        *(f16x8*)((_Float16*)outp + o) = h;
    }
}

__global__ void pull3(const float* __restrict__ t, const float* __restrict__ prev,
                      const int* __restrict__ rp, const unsigned* __restrict__ ev,
                      float* __restrict__ outp, float alpha, int N) {
    int node = blockIdx.x * blockDim.x + threadIdx.x;
    if (node >= N) return;
    int b = rp[node], e = rp[node + 1];
    float a0 = 0.f, a1 = 0.f, a2 = 0.f;
    for (int j = b; j < e; ++j) {
        unsigned v = ev[j];
        float w = ev_w(v);
        const float* r = t + (size_t)ev_src(v) * 3;
        a0 += w * r[0]; a1 += w * r[1]; a2 += w * r[2];
    }
    float r0 = alpha * a0, r1 = alpha * a1, r2 = alpha * a2;
    if (prev) {
        r0 -= prev[node * 3 + 0];
        r1 -= prev[node * 3 + 1];
        r2 -= prev[node * 3 + 2];
    }
    outp[node * 3 + 0] = r0;
    outp[node * 3 + 1] = r1;
    outp[node * 3 + 2] = r2;
}

// ---------------- fused BN-finalize + weight prep + bias --------------------
__global__ __launch_bounds__(256)
void wfuse_kernel(const float* __restrict__ stats, const float* __restrict__ g,
                  const float* __restrict__ be, const float* __restrict__ W,
                  const float* __restrict__ b, _Float16* __restrict__ Wt,
                  float* __restrict__ bias2, float* __restrict__ bnp, float invN) {
    int tid = threadIdx.x;
    if (blockIdx.x < 256) {
        int idx = blockIdx.x * 256 + tid;   // 65536 = n(128) x k(512)
        int n = idx >> 9, k = idx & 511;
        int sel = k >> 7, kk = k & 127;
        int o = kk * 128 + n;
        float v;
        if (sel == 0) {
            float s0 = 0.f, s1 = 0.f;
#pragma unroll 4
            for (int t = 0; t < NSLOT; ++t) {
                s0 += stats[t * 256 + kk];
                s1 += stats[t * 256 + 128 + kk];
            }
            float m = s0 * invN;
            float var = s1 * invN - m * m;
            float sc = g[kk] * rsqrtf(var + 1e-5f);
            v = (W[o] - W[2 * 16384 + o]) * sc;
        } else if (sel == 1) v = W[16384 + o] - 3.f * W[3 * 16384 + o];
        else if (sel == 2)   v = 2.f * W[2 * 16384 + o];
        else                 v = 4.f * W[3 * 16384 + o];
        Wt[(size_t)((k >> 3) * 128 + n) * 8 + (k & 7)] = (_Float16)v;
    } else {
        __shared__ float sh[128];
        if (tid < 128) {
            float s0 = 0.f, s1 = 0.f;
#pragma unroll 4
            for (int t = 0; t < NSLOT; ++t) {
                s0 += stats[t * 256 + tid];
                s1 += stats[t * 256 + 128 + tid];
            }
            float m = s0 * invN;
            float var = s1 * invN - m * m;
            float sc = g[tid] * rsqrtf(var + 1e-5f);
            float shf = be[tid] - m * sc;
            bnp[tid] = sc;
            bnp[128 + tid] = shf;
            sh[tid] = shf;
        }
        __syncthreads();
        if (tid < 128) {
            float s = b[tid];
            for (int k = 0; k < 128; ++k)
                s += sh[k] * (W[k * 128 + tid] - W[2 * 16384 + k * 128 + tid]);
            bias2[tid] = s;
        }
    }
}

// ---------------- MFMA Cheb GEMM, LDS-staged A, fused BN-stats epilogue -----
template <int ACT, int OUTH, int STATS>
__global__ __launch_bounds__(256)
void gemm_mfma(const __half* __restrict__ T0, const __half* __restrict__ T1,
               const __half* __restrict__ T2, const __half* __restrict__ T3,
               const _Float16* __restrict__ Wt, const float* __restrict__ bias2,
               __half* __restrict__ outh, float* __restrict__ outf,
               float* __restrict__ stats, int N) {
    __shared__ __align__(16) _Float16 As[4][32][136];
    __shared__ float s_sum[128];
    __shared__ float s_sq[128];
    int tid = threadIdx.x;
    int wave = tid >> 6, lane = tid & 63;
    int row0 = blockIdx.x * 32;

    if (STATS && tid < 128) { s_sum[tid] = 0.f; s_sq[tid] = 0.f; }

    // ---- stage A: wave w loads table w (32 rows x 128 ch fp16 = 8 KB) ----
    {
        const __half* Ts[4] = {T0, T1, T2, T3};
        const _Float16* Tp = (const _Float16*)Ts[wave];
        int lr = lane >> 4;           // row-sub 0..3
        int ko = (lane & 15) * 8;     // k offset (halves)
        f16x8 v[8];
#pragma unroll
        for (int t = 0; t < 8; ++t) {
            int gr = min(row0 + t * 4 + lr, N - 1);
            v[t] = *(const f16x8*)(Tp + (size_t)gr * HDIM + ko);
        }
#pragma unroll
        for (int t = 0; t < 8; ++t)
            *(f16x8*)&As[wave][t * 4 + lr][ko] = v[t];
    }
    __syncthreads();

    int wr = wave >> 1, wc = wave & 1;
    int m = lane & 15, quad = lane >> 4;
    int nbase = wc * 64 + m;

    f32x4 acc[4];
#pragma unroll
    for (int ct = 0; ct < 4; ++ct) acc[ct] = (f32x4){0.f, 0.f, 0.f, 0.f};

#pragma unroll
    for (int kt = 0; kt < 4; ++kt) {
#pragma unroll
        for (int sel = 0; sel < 4; ++sel) {
            f16x8 a = *(const f16x8*)&As[sel][wr * 16 + m][kt * 32 + quad * 8];
            int c0 = sel * 16 + kt * 4 + quad;        // k-chunk index
#pragma unroll
            for (int ct = 0; ct < 4; ++ct) {
                f16x8 b0 = *(const f16x8*)(Wt + ((size_t)c0 * 128 + nbase + ct * 16) * 8);
                acc[ct] = __builtin_amdgcn_mfma_f32_16x16x32_f16(a, b0, acc[ct], 0, 0, 0);
            }
        }
    }

    // epilogue (+ optional per-column stats accumulation)
#pragma unroll
    for (int ct = 0; ct < 4; ++ct) {
        int col = wc * 64 + ct * 16 + m;
        float bv = bias2[col];
        float lsum = 0.f, lsq = 0.f;
#pragma unroll
        for (int r = 0; r < 4; ++r) {
            int drow = row0 + wr * 16 + quad * 4 + r;
            if (drow < N) {
                float v = acc[ct][r] + bv;
                if (ACT == 1) v = v >= 0.f ? v : 0.01f * v;
                else if (ACT == 2) v = fmaxf(v, 0.f);
                if (OUTH) outh[(size_t)drow * HDIM + col] = __float2half(v);
                else      outf[(size_t)drow * HDIM + col] = v;
                if (STATS) {
                    float vh = OUTH ? __half2float(__float2half(v)) : v;
                    lsum += vh; lsq += vh * vh;
                }
            }
        }
        if (STATS) {
            atomicAdd(&s_sum[col], lsum);
            atomicAdd(&s_sq[col], lsq);
        }
    }
    if (STATS) {
        __syncthreads();
        if (tid < 128) {
            float* sp = stats + (size_t)(blockIdx.x & (NSLOT - 1)) * 256;
            atomicAdd(&sp[tid], s_sum[tid]);
            atomicAdd(&sp[128 + tid], s_sq[tid]);
        }
    }
}

// ---------------- layer-1 (input dim 3) fused GEMM, grid-stride ------------
__global__ __launch_bounds__(256)
void gemm1_kernel(const float* __restrict__ x, const float* __restrict__ t1,
                  const float* __restrict__ t2, const float* __restrict__ t3,
                  const float* __restrict__ W1, const float* __restrict__ b1,
                  __half* __restrict__ out, float* __restrict__ stats, int N) {
    __shared__ float s_sum[128];
    __shared__ float s_sq[128];
    int tid = threadIdx.x;
    int c = tid & 127;
    if (tid < 128) { s_sum[tid] = 0.f; s_sq[tid] = 0.f; }
    __syncthreads();
    float wreg[12];
#pragma unroll
    for (int i = 0; i < 12; ++i) wreg[i] = W1[i * 128 + c];
    float bias = b1[c];
    const float* Ts[4] = {x, t1, t2, t3};
    float lsum = 0.f, lsq = 0.f;
    for (int row = blockIdx.x * 2 + (tid >> 7); row < N; row += gridDim.x * 2) {
        float v = bias;
#pragma unroll
        for (int k = 0; k < 4; ++k) {
            const float* t = Ts[k];
#pragma unroll
            for (int d = 0; d < 3; ++d)
                v += t[row * 3 + d] * wreg[k * 3 + d];
        }
        v = v >= 0.f ? v : 0.01f * v;   // leaky_relu
        out[(size_t)row * HDIM + c] = __float2half(v);
        lsum += v; lsq += v * v;
    }
    atomicAdd(&s_sum[c], lsum);
    atomicAdd(&s_sq[c], lsq);
    __syncthreads();
    if (tid < 128) {
        float* sp = stats + (size_t)(blockIdx.x & (NSLOT - 1)) * 256;
        atomicAdd(&sp[tid], s_sum[tid]);
        atomicAdd(&sp[128 + tid], s_sq[tid]);
    }
}

// ---------------- final: L2-normalize row + project to 3 ----------------
__global__ void final_kernel(const float* __restrict__ Z, const float* __restrict__ Wm,
                             const float* __restrict__ bm, float* __restrict__ out, int N) {
    int gid = blockIdx.x * blockDim.x + threadIdx.x;
    int node = gid >> 6;
    int lane = threadIdx.x & 63;
    if (node >= N) return;
    const float* z = Z + (size_t)node * HDIM;
    float z0 = z[lane], z1 = z[lane + 64];
    float sq = z0 * z0 + z1 * z1;
    float d0 = z0 * Wm[lane * 3 + 0] + z1 * Wm[(lane + 64) * 3 + 0];
    float d1 = z0 * Wm[lane * 3 + 1] + z1 * Wm[(lane + 64) * 3 + 1];
    float d2 = z0 * Wm[lane * 3 + 2] + z1 * Wm[(lane + 64) * 3 + 2];
#pragma unroll
    for (int off = 32; off > 0; off >>= 1) {
        sq += __shfl_down(sq, off);
        d0 += __shfl_down(d0, off);
        d1 += __shfl_down(d1, off);
        d2 += __shfl_down(d2, off);
    }
    if (lane == 0) {
        float inv = 1.f / fmaxf(sqrtf(sq), 1e-12f);
        out[node * 3 + 0] = d0 * inv + bm[0];
        out[node * 3 + 1] = d1 * inv + bm[1];
        out[node * 3 + 2] = d2 * inv + bm[2];
    }
}

// ---------------- host ----------------

extern "C" void kernel_launch(void* const* d_in, const int* in_sizes, int n_in,
                              void* d_out, int out_size, void* d_ws, size_t ws_size,
                              hipStream_t stream) {
    const float* x  = (const float*)d_in[0];
    const int*   ei = (const int*)d_in[1];
    const float* W1 = (const float*)d_in[2];
    const float* b1 = (const float*)d_in[3];
    const float* W2 = (const float*)d_in[4];
    const float* b2 = (const float*)d_in[5];
    const float* W3 = (const float*)d_in[6];
    const float* b3 = (const float*)d_in[7];
    const float* W4 = (const float*)d_in[8];
    const float* b4 = (const float*)d_in[9];
    const float* g1 = (const float*)d_in[10];
    const float* be1 = (const float*)d_in[11];
    const float* g2 = (const float*)d_in[12];
    const float* be2 = (const float*)d_in[13];
    const float* g3 = (const float*)d_in[14];
    const float* be3 = (const float*)d_in[15];
    const float* Wm = (const float*)d_in[16];
    const float* bm = (const float*)d_in[17];
    float* out = (float*)d_out;

    const int N = in_sizes[0] / 3;
    const int E = in_sizes[1] / 2;
    const size_t NH = (size_t)N * HDIM;
    const int* src = ei;
    const int* dst = ei + E;

    const size_t STB = (size_t)NSLOT * 256 * 4;

    // ---- workspace layout (cursor + 3 stats buffers contiguous: one memset) ----
    char* base = (char*)d_ws;
    int* cursor  = (int*)base;           base += (size_t)N * 4;
    float* statsA = (float*)base;        base += STB;
    float* statsB = (float*)base;        base += STB;
    float* statsC = (float*)base;        base += STB;
    const size_t ZB = (size_t)N * 4 + 3 * STB;   // bytes zeroed upfront

    int* partS  = (int*)base;            base += (size_t)NSLICE * N * 4;
    int* partD  = (int*)base;            base += (size_t)NSLICE * N * 4;
    int* degD   = (int*)base;            base += (size_t)N * 4;
    int* rp     = (int*)base;            base += (size_t)(N + 2) * 4;
    int* bsum   = (int*)base;            base += (size_t)1024 * 4;
    unsigned* ev = (unsigned*)base;      base += (size_t)E * 4;
    float* dinv = (float*)base;          base += (size_t)N * 4;
    __half* Za  = (__half*)base;         base += NH * 2;
    __half* Zb  = (__half*)base;         base += NH * 2;
    __half* T1  = (__half*)base;         base += NH * 2;
    __half* T2  = (__half*)base;         base += NH * 2;
    __half* T3  = (__half*)base;         base += NH * 2;
    float* Zf   = (float*)base;          base += NH * 4;   // layer-4 out, fp32
    float* x1   = (float*)base;          base += (size_t)N * 3 * 4;
    float* x2   = (float*)base;          base += (size_t)N * 3 * 4;
    float* x3   = (float*)base;          base += (size_t)N * 3 * 4;
    float* bnp1  = (float*)base;         base += 256 * 4;
    float* bnp2  = (float*)base;         base += 256 * 4;
    float* bnp3  = (float*)base;         base += 256 * 4;
    _Float16* Wt = (_Float16*)base;      base += (size_t)65536 * 2;
    float* bias2 = (float*)base;         base += 128 * 4;

    const int EB = (E + 255) / 256;
    const int NB = (N + 255) / 256;
    const int GB = (N + 31) / 32;         // mfma gemm row tiles (32 rows)
    const int PB = (N + 3) / 4;           // pull128 blocks (4 nodes/block)
    const int NSEG = (N + SEGSZ - 1) / SEGSZ;
    const float invN = 1.f / (float)N;

    // --- single upfront zero of cursor + all stats buffers ---
    hipMemsetAsync(cursor, 0, ZB, stream);

    // --- CSR build + edge weights ---
    hist_kernel<<<NSEG * NSLICE, 256, 0, stream>>>(src, dst, partS, partD, NSEG, N, E);
    reduce_kernel<<<NB, 256, 0, stream>>>(partS, partD, dinv, degD, bsum, N);
    scanp2_kernel<<<1, 1024, 0, stream>>>(bsum, NB);
    scanp3_kernel<<<NB, 256, 0, stream>>>(degD, bsum, rp, N, E);
    scatter_kernel<<<EB, 256, 0, stream>>>(src, dst, dinv, rp, cursor, ev, E);

    // --- layer 1 (dim 3) -> Za (fp16) + statsA ---
    pull3<<<NB, 256, 0, stream>>>(x,  nullptr, rp, ev, x1, 1.f, N);
    pull3<<<NB, 256, 0, stream>>>(x1, x,       rp, ev, x2, 2.f, N);
    pull3<<<NB, 256, 0, stream>>>(x2, x1,      rp, ev, x3, 2.f, N);
    gemm1_kernel<<<512, 256, 0, stream>>>(x, x1, x2, x3, W1, b1, Za, statsA, N);

    // --- layer 2 (leaky + BN): U-chain from BN(Za,bnp1) -> Zb (stats -> B) ---
    wfuse_kernel<<<257, 256, 0, stream>>>(statsA, g1, be1, W2, b2, Wt, bias2, bnp1, invN);
    pull128<1><<<PB, 256, 0, stream>>>(Za, rp, ev, bnp1, T1, N);
    pull128<0><<<PB, 256, 0, stream>>>(T1, rp, ev, nullptr, T2, N);
    pull128<0><<<PB, 256, 0, stream>>>(T2, rp, ev, nullptr, T3, N);
    gemm_mfma<1, 1, 1><<<GB, 256, 0, stream>>>(Za, T1, T2, T3, Wt, bias2, Zb, nullptr, statsB, N);

    // --- layer 3 (relu + BN): U-chain from BN(Zb,bnp2) -> Za (stats -> C) ---
    wfuse_kernel<<<257, 256, 0, stream>>>(statsB, g2, be2, W3, b3, Wt, bias2, bnp2, invN);
    pull128<1><<<PB, 256, 0, stream>>>(Zb, rp, ev, bnp2, T1, N);
    pull128<0><<<PB, 256, 0, stream>>>(T1, rp, ev, nullptr, T2, N);
    pull128<0><<<PB, 256, 0, stream>>>(T2, rp, ev, nullptr, T3, N);
    gemm_mfma<2, 1, 1><<<GB, 256, 0, stream>>>(Zb, T1, T2, T3, Wt, bias2, Za, nullptr, statsC, N);

    // --- layer 4 (no act/BN): U-chain from BN(Za,bnp3) -> Zf (fp32) ---
    wfuse_kernel<<<257, 256, 0, stream>>>(statsC, g3, be3, W4, b4, Wt, bias2, bnp3, invN);
    pull128<1><<<PB, 256, 0, stream>>>(Za, rp, ev, bnp3, T1, N);
    pull128<0><<<PB, 256, 0, stream>>>(T1, rp, ev, nullptr, T2, N);
    pull128<0><<<PB, 256, 0, stream>>>(T2, rp, ev, nullptr, T3, N);
    gemm_mfma<0, 0, 0><<<GB, 256, 0, stream>>>(Za, T1, T2, T3, Wt, bias2, nullptr, Zf, nullptr, N);

    // --- normalize + project ---
    final_kernel<<<(N * 64 + 255) / 256, 256, 0, stream>>>(Zf, Wm, bm, out, N);
}